// Round 20
// baseline (576.714 us; speedup 1.0000x reference)
//
#include <hip/hip_runtime.h>
#include <hip/hip_fp16.h>

#define BN 256              // nodes per bucket
#define MAXBUCK 512         // bucket-count capacity (N <= 131072)
#define CAP 10240           // bucket staging (mean 8184, +22 sigma)
#define TANH_SCALE 2.8853900817779268f   // 2*log2(e)

typedef float f32x2 __attribute__((ext_vector_type(2)));

__device__ __forceinline__ void pk_add(f32x2& acc, f32x2 v) {
    asm("v_pk_add_f32 %0, %1, %0" : "+v"(acc) : "v"(v));
}

// ---------------- bucket build ----------------

__global__ void k_bcnt(const int* __restrict__ dst, int* __restrict__ bcnt,
                       int E, int nbuck) {
    __shared__ int h[MAXBUCK];
    for (int i = threadIdx.x; i < nbuck; i += blockDim.x) h[i] = 0;
    __syncthreads();
    for (int e = blockIdx.x * blockDim.x + threadIdx.x; e < E; e += gridDim.x * blockDim.x)
        atomicAdd(&h[dst[e] >> 8], 1);
    __syncthreads();
    for (int i = threadIdx.x; i < nbuck; i += blockDim.x)
        if (h[i]) atomicAdd(&bcnt[i], h[i]);
}

__global__ void k_bscan(const int* __restrict__ bcnt, int* __restrict__ boff,
                        int* __restrict__ gcur, int nbuck, int total) {
    __shared__ int sm[256];
    __shared__ int carry;
    int t = threadIdx.x;
    if (t == 0) carry = 0;
    __syncthreads();
    for (int base = 0; base < nbuck; base += 256) {
        int v = (base + t < nbuck) ? bcnt[base + t] : 0;
        sm[t] = v;
        __syncthreads();
        #pragma unroll
        for (int d = 1; d < 256; d <<= 1) {
            int tv = (t >= d) ? sm[t - d] : 0;
            __syncthreads();
            sm[t] += tv;
            __syncthreads();
        }
        int excl = carry + sm[t] - v;
        if (base + t < nbuck) { boff[base + t] = excl; gcur[base + t] = excl; }
        __syncthreads();
        if (t == 0) carry += sm[255];
        __syncthreads();
    }
    if (t == 0) boff[nbuck] = total;
}

__global__ void k_bscatter(const int* __restrict__ src, const int* __restrict__ dst,
                           const float* __restrict__ ea, int* __restrict__ gcur,
                           uint2* __restrict__ rec, int E, int nbuck) {
    __shared__ int lcnt[MAXBUCK];
    __shared__ int lbase[MAXBUCK];
    const int nb = gridDim.x;
    const long c0 = (long)E * blockIdx.x / nb;
    const long c1 = (long)E * (blockIdx.x + 1) / nb;
    for (int i = threadIdx.x; i < nbuck; i += blockDim.x) lcnt[i] = 0;
    __syncthreads();
    for (long e = c0 + threadIdx.x; e < c1; e += blockDim.x)
        atomicAdd(&lcnt[dst[e] >> 8], 1);
    __syncthreads();
    for (int i = threadIdx.x; i < nbuck; i += blockDim.x) {
        int c = lcnt[i];
        lbase[i] = c ? atomicAdd(&gcur[i], c) : 0;
    }
    __syncthreads();
    for (int i = threadIdx.x; i < nbuck; i += blockDim.x) lcnt[i] = 0;
    __syncthreads();
    for (long e = c0 + threadIdx.x; e < c1; e += blockDim.x) {
        int d = dst[e];
        int b = d >> 8;
        int rank = atomicAdd(&lcnt[b], 1);
        unsigned meta = ((unsigned)(d & 255) << 17) | (unsigned)src[e];
        rec[lbase[b] + rank] = make_uint2(meta, __float_as_uint(ea[e]));
    }
}

__global__ void k_blocal(const uint2* __restrict__ rec, uint2* __restrict__ rec2,
                         int* __restrict__ srcs2, const int* __restrict__ boff,
                         int* __restrict__ off, int N, int E) {
    __shared__ uint2 sB[CAP];
    __shared__ int cnt[BN];
    __shared__ int base[BN];
    __shared__ int sm[BN];
    const int b = blockIdx.x;
    const int tid = threadIdx.x;
    int e0 = boff[b], e1 = boff[b + 1];
    int tot = e1 - e0;
    cnt[tid] = 0;
    __syncthreads();
    for (int i = tid; i < tot; i += 256)
        atomicAdd(&cnt[rec[e0 + i].x >> 17], 1);
    __syncthreads();
    int v = cnt[tid];
    sm[tid] = v;
    __syncthreads();
    #pragma unroll
    for (int d = 1; d < 256; d <<= 1) {
        int tv = (tid >= d) ? sm[tid - d] : 0;
        __syncthreads();
        sm[tid] += tv;
        __syncthreads();
    }
    base[tid] = sm[tid] - v;                       // exclusive
    int n = b * BN + tid;
    if (n < N) off[n] = e0 + base[tid];
    if (b == 0 && tid == 0) off[N] = E;
    cnt[tid] = 0;
    __syncthreads();
    for (int i = tid; i < tot; i += 256) {
        uint2 r = rec[e0 + i];
        int dl = r.x >> 17;
        int rank = atomicAdd(&cnt[dl], 1);
        unsigned s = r.x & 0x1FFFFu;
        float eaf = __uint_as_float(r.y);
        unsigned hb = (unsigned)__half_as_ushort(__float2half(eaf));
        sB[base[dl] + rank] = make_uint2(s, (hb << 16) | hb);
    }
    __syncthreads();
    for (int i = tid; i < tot; i += 256) {         // coalesced write-back
        uint2 r = sB[i];
        rec2[e0 + i] = r;
        srcs2[e0 + i] = (int)r.x;
    }
}

// dummy rows: Mh halves row N = +inf (edge contributions vanish), sim halves = 0
__global__ void k_initdummy(__half* __restrict__ Mh0, __half* __restrict__ Mh1,
                            __half* __restrict__ s0, __half* __restrict__ s1, int N) {
    int i = threadIdx.x;                           // 16 threads
    if (i < 16) {
        Mh0[N * 16 + i] = __ushort_as_half((unsigned short)0x7C00);
        Mh1[N * 16 + i] = __ushort_as_half((unsigned short)0x7C00);
        s0[N * 16 + i] = __ushort_as_half((unsigned short)0);
        s1[N * 16 + i] = __ushort_as_half((unsigned short)0);
    }
}

// ---------------- per-layer kernels ----------------

// layer-0: M = (x@Wx0 + p@Wp0) * TANH_SCALE, fp16 output split into column halves
__global__ void k_node_gemm5(const float* __restrict__ h, const float* __restrict__ p,
                             const float* __restrict__ Wx, const float* __restrict__ Wp,
                             __half* __restrict__ Mh0, __half* __restrict__ Mh1,
                             int n_nodes) {
    __shared__ float sWx[5 * 32];
    __shared__ float sWp[96];
    for (int i = threadIdx.x; i < 5 * 32; i += blockDim.x) sWx[i] = Wx[i] * TANH_SCALE;
    if (threadIdx.x < 96) sWp[threadIdx.x] = Wp[threadIdx.x] * TANH_SCALE;
    __syncthreads();
    const int k = threadIdx.x & 31;
    int n = blockIdx.x * (blockDim.x >> 5) + (threadIdx.x >> 5);
    if (n >= n_nodes) return;
    float hv = (k < 5) ? h[n * 5 + k] : 0.0f;
    float pv = (k < 3) ? p[n * 3 + k] : 0.0f;
    float acc = 0.0f;
    #pragma unroll
    for (int j = 0; j < 5; ++j) acc = fmaf(__shfl(hv, j, 32), sWx[j * 32 + k], acc);
    #pragma unroll
    for (int j = 0; j < 3; ++j) acc = fmaf(__shfl(pv, j, 32), sWp[j * 32 + k], acc);
    __half hh = __float2half(acc);
    if (k < 16) Mh0[n * 16 + k] = hh; else Mh1[n * 16 + (k & 15)] = hh;
}

// mid-layer: M = (hF@Wx + p@Wp) * TANH_SCALE, hF is f32 [N][32] (sequential read)
__global__ void k_node_gemm32(const float* __restrict__ hF, const float* __restrict__ p,
                              const float* __restrict__ Wx, const float* __restrict__ Wp,
                              __half* __restrict__ Mh0, __half* __restrict__ Mh1,
                              int n_nodes) {
    __shared__ float sWx[1024];
    __shared__ float sWp[96];
    for (int i = threadIdx.x; i < 1024; i += blockDim.x) sWx[i] = Wx[i] * TANH_SCALE;
    if (threadIdx.x < 96) sWp[threadIdx.x] = Wp[threadIdx.x] * TANH_SCALE;
    __syncthreads();
    const int k = threadIdx.x & 31;
    int n = blockIdx.x * (blockDim.x >> 5) + (threadIdx.x >> 5);
    if (n >= n_nodes) return;
    float hv = hF[n * 32 + k];
    float pv = (k < 3) ? p[n * 3 + k] : 0.0f;
    float acc = 0.0f;
    #pragma unroll
    for (int j = 0; j < 32; ++j) acc = fmaf(__shfl(hv, j, 32), sWx[j * 32 + k], acc);
    #pragma unroll
    for (int j = 0; j < 3; ++j) acc = fmaf(__shfl(pv, j, 32), sWp[j * 32 + k], acc);
    __half hh = __float2half(acc);
    if (k < 16) Mh0[n * 16 + k] = hh; else Mh1[n * 16 + (k & 15)] = hh;
}

// edge half-pass: gathers from a 3.2MB half-table (L2-resident per XCD).
// lane c = l&7 owns column pair (2c,2c+1) of this half; q = l>>3 -> 4 edges/iter.
__global__ void k_edge_half(const __half* __restrict__ MhH, const float* __restrict__ p,
                            const int* __restrict__ off, const uint2* __restrict__ rec,
                            const float* __restrict__ WpH, const float* __restrict__ WeH,
                            const float* __restrict__ biasH,
                            __half* __restrict__ simH, int N) {
    __shared__ uint2 stage[8][32];
    const int l = threadIdx.x & 31;
    const int c = l & 7;
    const int q = l >> 3;
    const int grp = threadIdx.x >> 5;
    int n = blockIdx.x * 8 + grp;
    if (n >= N) return;

    const __half2* MhH2 = (const __half2*)MhH;

    float2 wef = ((const float2*)WeH)[c];
    __half2 we2 = __floats2half2_rn(wef.x * TANH_SCALE, wef.y * TANH_SCALE);
    float2 b2  = ((const float2*)biasH)[c];
    float2 wp0 = ((const float2*)WpH)[c];
    float2 wp1 = ((const float2*)(WpH + 32))[c];
    float2 wp2 = ((const float2*)(WpH + 64))[c];
    float pn = (l < 3) ? p[n * 3 + l] : 0.0f;
    float pn0 = __shfl(pn, 0, 32), pn1 = __shfl(pn, 1, 32), pn2 = __shfl(pn, 2, 32);
    __half2 cnst2 = __floats2half2_rn(
        (b2.x - (pn0 * wp0.x + pn1 * wp1.x + pn2 * wp2.x)) * TANH_SCALE,
        (b2.y - (pn0 * wp0.y + pn1 * wp1.y + pn2 * wp2.y)) * TANH_SCALE);
    const __half2 one2  = __floats2half2_rn(1.0f, 1.0f);
    const __half2 zero2 = __floats2half2_rn(0.0f, 0.0f);

    const unsigned long long* rec8 = (const unsigned long long*)rec;
    float fx = 0.0f, fy = 0.0f;
    int e0 = off[n], e1 = off[n + 1];
    for (int base = e0; base < e1; base += 32) {
        int m = min(32, e1 - base);
        // nontemporal stream read: don't evict the resident half-table
        unsigned long long rv = (l < m) ? __builtin_nontemporal_load(rec8 + base + l)
                                        : (unsigned long long)(unsigned)N;  // dummy row
        stage[grp][l] = make_uint2((unsigned)rv, (unsigned)(rv >> 32));
        __half2 mv[8], av[8];
        #pragma unroll
        for (int u = 0; u < 8; ++u) {
            uint2 e = stage[grp][4 * u + q];      // uniform per q-slice
            unsigned eb = e.y;
            av[u] = *(const __half2*)&eb;
            mv[u] = MhH2[e.x * 8 + c];            // 8 half2 gathers, L2-hit
        }
        __half2 acc2 = zero2;
        #pragma unroll
        for (int u = 0; u < 8; ++u) {
            __half2 arg = __hadd2(__hfma2(av[u], we2, cnst2), mv[u]);
            acc2 = __hadd2(acc2, h2rcp(__hadd2(h2exp2(arg), one2)));  // dummy->0
        }
        fx += __low2float(acc2);
        fy += __high2float(acc2);
    }
    fx += __shfl_xor(fx, 8, 32); fx += __shfl_xor(fx, 16, 32);
    fy += __shfl_xor(fy, 8, 32); fy += __shfl_xor(fy, 16, 32);
    float deg = (float)(e1 - e0);
    if (l < 8)
        ((__half2*)simH)[n * 8 + c] =
            __floats2half2_rn(fmaf(-2.0f, fx, deg), fmaf(-2.0f, fy, deg));
}

// prop half-pass: h_half[n] = sum of sim_half[src]; writes f32 hF columns
__global__ void k_prop_half(const __half* __restrict__ simH, const int* __restrict__ off,
                            const int* __restrict__ srcs, float* __restrict__ hF,
                            int colbase, int N) {
    __shared__ int stageS[8][32];
    const int l = threadIdx.x & 31;
    const int c = l & 7;
    const int q = l >> 3;
    const int grp = threadIdx.x >> 5;
    int n = blockIdx.x * 8 + grp;
    if (n >= N) return;

    const __half2* sim2 = (const __half2*)simH;
    f32x2 facc = {0.0f, 0.0f};
    int e0 = off[n], e1 = off[n + 1];
    for (int base = e0; base < e1; base += 32) {
        int m = min(32, e1 - base);
        stageS[grp][l] = (l < m) ? __builtin_nontemporal_load(srcs + base + l) : N;
        __half2 v[8];
        #pragma unroll
        for (int u = 0; u < 8; ++u) {
            int s = stageS[grp][4 * u + q];
            v[u] = sim2[s * 8 + c];                // 8 half2 gathers, L2-hit
        }
        #pragma unroll
        for (int u = 0; u < 8; ++u) {
            float2 fv = __half22float2(v[u]);
            f32x2 t = {fv.x, fv.y};
            pk_add(facc, t);                       // exact packed f32 add
        }
    }
    float fx = facc.x, fy = facc.y;
    fx += __shfl_xor(fx, 8, 32); fx += __shfl_xor(fx, 16, 32);
    fy += __shfl_xor(fy, 8, 32); fy += __shfl_xor(fy, 16, 32);
    if (l < 8)
        ((float2*)(hF + n * 32 + colbase))[c] = make_float2(fx, fy);
}

// ---------------- pooling + head ----------------

__global__ void k_pool(const float* __restrict__ h, const int* __restrict__ batch,
                       const float* __restrict__ Wh, const float* __restrict__ bh,
                       float* __restrict__ out, int n_nodes, int n_graphs) {
    __shared__ int sLo, sHi;
    __shared__ float red[256];
    int g = blockIdx.x;
    if (threadIdx.x == 0) {
        int lo = 0, hi = n_nodes;
        while (lo < hi) { int m = (lo + hi) >> 1; if (batch[m] < g) lo = m + 1; else hi = m; }
        sLo = lo;
        lo = 0; hi = n_nodes; int g1 = g + 1;
        while (lo < hi) { int m = (lo + hi) >> 1; if (batch[m] < g1) lo = m + 1; else hi = m; }
        sHi = lo;
    }
    __syncthreads();
    int lo = sLo, hi = sHi;
    int k = threadIdx.x & 31, r = threadIdx.x >> 5;
    float acc = 0.0f;
    for (int n = lo + r; n < hi; n += 8) acc += h[n * 32 + k];
    red[threadIdx.x] = acc;
    __syncthreads();
    if (threadIdx.x < 32) {
        float s = 0.0f;
        #pragma unroll
        for (int r2 = 0; r2 < 8; ++r2) s += red[r2 * 32 + k];
        float c = (float)(hi - lo);
        float rep = s / fmaxf(c, 1.0f);
        out[n_graphs + g * 32 + k] = rep;
        float t = rep * Wh[k];
        #pragma unroll
        for (int d = 16; d > 0; d >>= 1) t += __shfl_down(t, d, 32);
        if (k == 0) out[g] = t + bh[0];
    }
}

// ---------------- launch ----------------

extern "C" void kernel_launch(void* const* d_in, const int* in_sizes, int n_in,
                              void* d_out, int out_size, void* d_ws, size_t ws_size,
                              hipStream_t stream) {
    const float* x   = (const float*)d_in[0];
    const float* p   = (const float*)d_in[1];
    const float* ea  = (const float*)d_in[2];
    const float* Wx0 = (const float*)d_in[3];
    const float* Wx1 = (const float*)d_in[4];
    const float* Wx2 = (const float*)d_in[5];
    const float* Wp0 = (const float*)d_in[6];
    const float* Wp1 = (const float*)d_in[7];
    const float* Wp2 = (const float*)d_in[8];
    const float* We0 = (const float*)d_in[9];
    const float* We1 = (const float*)d_in[10];
    const float* We2 = (const float*)d_in[11];
    const float* b0  = (const float*)d_in[12];
    const float* b1  = (const float*)d_in[13];
    const float* b2  = (const float*)d_in[14];
    const float* Wh  = (const float*)d_in[15];
    const float* bh  = (const float*)d_in[16];
    const int* edge_index = (const int*)d_in[17];
    const int* batch      = (const int*)d_in[18];

    const int N = in_sizes[0] / 5;
    const int E = in_sizes[17] / 2;
    const int G = out_size / 33;
    const int nbuck = (N + BN - 1) / BN;     // 391 for N=100000

    const int* srcp = edge_index;
    const int* dstp = edge_index + E;

    char* w = (char*)d_ws;
    auto alloc = [&](size_t bytes) -> void* {
        void* r = (void*)w;
        w += (bytes + 255) & ~(size_t)255;
        return r;
    };
    int*    bcnt  = (int*)alloc((size_t)nbuck * 4);
    int*    boff  = (int*)alloc((size_t)(nbuck + 1) * 4);
    int*    gcur  = (int*)alloc((size_t)nbuck * 4);
    int*    off   = (int*)alloc((size_t)(N + 1) * 4);
    uint2*  rec   = (uint2*)alloc((size_t)E * 8);
    uint2*  rec2  = (uint2*)alloc((size_t)E * 8);
    int*    srcs2 = (int*)alloc((size_t)E * 4);
    __half* Mh0   = (__half*)alloc((size_t)(N + 1) * 16 * 2);   // column halves
    __half* Mh1   = (__half*)alloc((size_t)(N + 1) * 16 * 2);
    __half* sim0  = (__half*)alloc((size_t)(N + 1) * 16 * 2);
    __half* sim1  = (__half*)alloc((size_t)(N + 1) * 16 * 2);
    float*  hF    = (float*)alloc((size_t)N * 32 * 4);

    // build: bucket sort (BN=256) -> within-bucket node sort (LDS-staged) -> CSR
    (void)hipMemsetAsync(bcnt, 0, (size_t)nbuck * 4, stream);
    k_bcnt<<<1024, 256, 0, stream>>>(dstp, bcnt, E, nbuck);
    k_bscan<<<1, 256, 0, stream>>>(bcnt, boff, gcur, nbuck, E);
    k_bscatter<<<256, 1024, 0, stream>>>(srcp, dstp, ea, gcur, rec, E, nbuck);
    k_blocal<<<nbuck, 256, 0, stream>>>(rec, rec2, srcs2, boff, off, N, E);
    k_initdummy<<<1, 64, 0, stream>>>(Mh0, Mh1, sim0, sim1, N);

    const int NB = (N + 7) / 8;   // 8 node-groups (32 lanes) per 256-thread block

    // layer 0
    k_node_gemm5<<<NB, 256, 0, stream>>>(x, p, Wx0, Wp0, Mh0, Mh1, N);
    k_edge_half<<<NB, 256, 0, stream>>>(Mh0, p, off, rec2, Wp0, We0, b0, sim0, N);
    k_edge_half<<<NB, 256, 0, stream>>>(Mh1, p, off, rec2, Wp0 + 16, We0 + 16, b0 + 16, sim1, N);
    k_prop_half<<<NB, 256, 0, stream>>>(sim0, off, srcs2, hF, 0, N);
    k_prop_half<<<NB, 256, 0, stream>>>(sim1, off, srcs2, hF, 16, N);
    k_node_gemm32<<<NB, 256, 0, stream>>>(hF, p, Wx1, Wp1, Mh0, Mh1, N);
    // layer 1
    k_edge_half<<<NB, 256, 0, stream>>>(Mh0, p, off, rec2, Wp1, We1, b1, sim0, N);
    k_edge_half<<<NB, 256, 0, stream>>>(Mh1, p, off, rec2, Wp1 + 16, We1 + 16, b1 + 16, sim1, N);
    k_prop_half<<<NB, 256, 0, stream>>>(sim0, off, srcs2, hF, 0, N);
    k_prop_half<<<NB, 256, 0, stream>>>(sim1, off, srcs2, hF, 16, N);
    k_node_gemm32<<<NB, 256, 0, stream>>>(hF, p, Wx2, Wp2, Mh0, Mh1, N);
    // layer 2
    k_edge_half<<<NB, 256, 0, stream>>>(Mh0, p, off, rec2, Wp2, We2, b2, sim0, N);
    k_edge_half<<<NB, 256, 0, stream>>>(Mh1, p, off, rec2, Wp2 + 16, We2 + 16, b2 + 16, sim1, N);
    k_prop_half<<<NB, 256, 0, stream>>>(sim0, off, srcs2, hF, 0, N);
    k_prop_half<<<NB, 256, 0, stream>>>(sim1, off, srcs2, hF, 16, N);

    // pool + head
    k_pool<<<G, 256, 0, stream>>>(hF, batch, Wh, bh, (float*)d_out, N, G);
}

// Round 21
// 397.770 us; speedup vs baseline: 1.4499x; 1.4499x over previous
//
#include <hip/hip_runtime.h>
#include <hip/hip_fp16.h>

#define K_DIM 32
#define BN 256              // nodes per bucket
#define MAXBUCK 512         // bucket-count capacity (N <= 131072)
#define CAP 10240           // bucket staging (mean 8184, +22 sigma)
#define TANH_SCALE 2.8853900817779268f   // 2*log2(e)

typedef float f32x2 __attribute__((ext_vector_type(2)));

__device__ __forceinline__ void pk_add(f32x2& acc, f32x2 v) {
    asm("v_pk_add_f32 %0, %1, %0" : "+v"(acc) : "v"(v));
}

// ---------------- bucket build ----------------

__global__ void k_bcnt(const int* __restrict__ dst, int* __restrict__ bcnt,
                       int E, int nbuck) {
    __shared__ int h[MAXBUCK];
    for (int i = threadIdx.x; i < nbuck; i += blockDim.x) h[i] = 0;
    __syncthreads();
    for (int e = blockIdx.x * blockDim.x + threadIdx.x; e < E; e += gridDim.x * blockDim.x)
        atomicAdd(&h[dst[e] >> 8], 1);
    __syncthreads();
    for (int i = threadIdx.x; i < nbuck; i += blockDim.x)
        if (h[i]) atomicAdd(&bcnt[i], h[i]);
}

__global__ void k_bscan(const int* __restrict__ bcnt, int* __restrict__ boff,
                        int* __restrict__ gcur, int nbuck, int total) {
    __shared__ int sm[256];
    __shared__ int carry;
    int t = threadIdx.x;
    if (t == 0) carry = 0;
    __syncthreads();
    for (int base = 0; base < nbuck; base += 256) {
        int v = (base + t < nbuck) ? bcnt[base + t] : 0;
        sm[t] = v;
        __syncthreads();
        #pragma unroll
        for (int d = 1; d < 256; d <<= 1) {
            int tv = (t >= d) ? sm[t - d] : 0;
            __syncthreads();
            sm[t] += tv;
            __syncthreads();
        }
        int excl = carry + sm[t] - v;
        if (base + t < nbuck) { boff[base + t] = excl; gcur[base + t] = excl; }
        __syncthreads();
        if (t == 0) carry += sm[255];
        __syncthreads();
    }
    if (t == 0) boff[nbuck] = total;
}

// bucket scatter, grid=256 x 1024 threads: per-(block,bucket) run ~32 records
__global__ void k_bscatter(const int* __restrict__ src, const int* __restrict__ dst,
                           const float* __restrict__ ea, int* __restrict__ gcur,
                           uint2* __restrict__ rec, int E, int nbuck) {
    __shared__ int lcnt[MAXBUCK];
    __shared__ int lbase[MAXBUCK];
    const int nb = gridDim.x;
    const long c0 = (long)E * blockIdx.x / nb;
    const long c1 = (long)E * (blockIdx.x + 1) / nb;
    for (int i = threadIdx.x; i < nbuck; i += blockDim.x) lcnt[i] = 0;
    __syncthreads();
    for (long e = c0 + threadIdx.x; e < c1; e += blockDim.x)
        atomicAdd(&lcnt[dst[e] >> 8], 1);
    __syncthreads();
    for (int i = threadIdx.x; i < nbuck; i += blockDim.x) {
        int c = lcnt[i];
        lbase[i] = c ? atomicAdd(&gcur[i], c) : 0;
    }
    __syncthreads();
    for (int i = threadIdx.x; i < nbuck; i += blockDim.x) lcnt[i] = 0;
    __syncthreads();
    for (long e = c0 + threadIdx.x; e < c1; e += blockDim.x) {
        int d = dst[e];
        int b = d >> 8;
        int rank = atomicAdd(&lcnt[b], 1);
        unsigned meta = ((unsigned)(d & 255) << 17) | (unsigned)src[e];
        rec[lbase[b] + rank] = make_uint2(meta, __float_as_uint(ea[e]));
    }
}

// within-bucket sort by node, staged in LDS -> fully coalesced write-back.
__global__ void k_blocal(const uint2* __restrict__ rec, uint2* __restrict__ rec2,
                         int* __restrict__ srcs2, const int* __restrict__ boff,
                         int* __restrict__ off, int N, int E) {
    __shared__ uint2 sB[CAP];
    __shared__ int cnt[BN];
    __shared__ int base[BN];
    __shared__ int sm[BN];
    const int b = blockIdx.x;
    const int tid = threadIdx.x;
    int e0 = boff[b], e1 = boff[b + 1];
    int tot = e1 - e0;
    cnt[tid] = 0;
    __syncthreads();
    for (int i = tid; i < tot; i += 256)
        atomicAdd(&cnt[rec[e0 + i].x >> 17], 1);
    __syncthreads();
    int v = cnt[tid];
    sm[tid] = v;
    __syncthreads();
    #pragma unroll
    for (int d = 1; d < 256; d <<= 1) {
        int tv = (tid >= d) ? sm[tid - d] : 0;
        __syncthreads();
        sm[tid] += tv;
        __syncthreads();
    }
    base[tid] = sm[tid] - v;                       // exclusive
    int n = b * BN + tid;
    if (n < N) off[n] = e0 + base[tid];
    if (b == 0 && tid == 0) off[N] = E;
    cnt[tid] = 0;
    __syncthreads();
    for (int i = tid; i < tot; i += 256) {
        uint2 r = rec[e0 + i];
        int dl = r.x >> 17;
        int rank = atomicAdd(&cnt[dl], 1);
        unsigned s = r.x & 0x1FFFFu;
        float eaf = __uint_as_float(r.y);
        unsigned hb = (unsigned)__half_as_ushort(__float2half(eaf));
        sB[base[dl] + rank] = make_uint2(s, (hb << 16) | hb);
    }
    __syncthreads();
    for (int i = tid; i < tot; i += 256) {         // coalesced write-back
        uint2 r = sB[i];
        rec2[e0 + i] = r;
        srcs2[e0 + i] = (int)r.x;
    }
}

// dummy rows: Mh[N] = +inf (edge contributions vanish), simh[N] = 0
__global__ void k_initdummy(__half* __restrict__ Mh, __half* __restrict__ simh, int N) {
    int i = threadIdx.x;                           // 32 threads
    Mh[N * 32 + i] = __ushort_as_half((unsigned short)0x7C00);
    simh[N * 32 + i] = __ushort_as_half((unsigned short)0);
}

// ---------------- per-layer kernels ----------------

// layer-0: M = (x@Wx0 + p@Wp0) * TANH_SCALE, fp16 output
__global__ void k_node_gemm5(const float* __restrict__ h, const float* __restrict__ p,
                             const float* __restrict__ Wx, const float* __restrict__ Wp,
                             __half* __restrict__ Mh, int n_nodes) {
    __shared__ float sWx[5 * 32];
    __shared__ float sWp[96];
    for (int i = threadIdx.x; i < 5 * 32; i += blockDim.x) sWx[i] = Wx[i] * TANH_SCALE;
    if (threadIdx.x < 96) sWp[threadIdx.x] = Wp[threadIdx.x] * TANH_SCALE;
    __syncthreads();
    const int k = threadIdx.x & 31;
    int n = blockIdx.x * (blockDim.x >> 5) + (threadIdx.x >> 5);
    if (n >= n_nodes) return;
    float hv = (k < 5) ? h[n * 5 + k] : 0.0f;
    float pv = (k < 3) ? p[n * 3 + k] : 0.0f;
    float acc = 0.0f;
    #pragma unroll
    for (int j = 0; j < 5; ++j) acc = fmaf(__shfl(hv, j, 32), sWx[j * 32 + k], acc);
    #pragma unroll
    for (int j = 0; j < 3; ++j) acc = fmaf(__shfl(pv, j, 32), sWp[j * 32 + k], acc);
    Mh[n * 32 + k] = __float2half(acc);
}

// sim[n][k] = deg(n) - 2 * sum_e rcp(exp2(M'[src] + cnst' + ea*we') + 1)
// packed half2; 8 half2 gathers in flight per inner step (r16 known-good)
__global__ void k_edge_msg(const __half* __restrict__ Mh, const float* __restrict__ p,
                           const int* __restrict__ off, const uint2* __restrict__ rec,
                           const float* __restrict__ Wp, const float* __restrict__ We,
                           const float* __restrict__ bias,
                           __half* __restrict__ simh, int N) {
    __shared__ uint2 stage[8][32];
    const int l = threadIdx.x & 31;
    const int c = l & 15;
    const int q = l >> 4;
    const int grp = threadIdx.x >> 5;
    int n = blockIdx.x * 8 + grp;
    if (n >= N) return;

    const __half2* Mh2 = (const __half2*)Mh;

    float2 wef = ((const float2*)We)[c];
    __half2 we2 = __floats2half2_rn(wef.x * TANH_SCALE, wef.y * TANH_SCALE);
    float2 b2  = ((const float2*)bias)[c];
    float2 wp0 = ((const float2*)Wp)[c];
    float2 wp1 = ((const float2*)(Wp + 32))[c];
    float2 wp2 = ((const float2*)(Wp + 64))[c];
    float pn = (l < 3) ? p[n * 3 + l] : 0.0f;
    float pn0 = __shfl(pn, 0, 32), pn1 = __shfl(pn, 1, 32), pn2 = __shfl(pn, 2, 32);
    __half2 cnst2 = __floats2half2_rn(
        (b2.x - (pn0 * wp0.x + pn1 * wp1.x + pn2 * wp2.x)) * TANH_SCALE,
        (b2.y - (pn0 * wp0.y + pn1 * wp1.y + pn2 * wp2.y)) * TANH_SCALE);
    const __half2 one2  = __floats2half2_rn(1.0f, 1.0f);
    const __half2 zero2 = __floats2half2_rn(0.0f, 0.0f);

    float fx = 0.0f, fy = 0.0f;
    int e0 = off[n], e1 = off[n + 1];
    for (int base = e0; base < e1; base += 32) {
        int m = min(32, e1 - base);
        uint2 r = (l < m) ? rec[base + l] : make_uint2((unsigned)N, 0u);  // dummy row
        stage[grp][l] = r;                        // wave-lockstep, no barrier
        __half2 acc2 = zero2;
        for (int j = 0; j < m; j += 16) {
            __half2 mv[8], av[8];
            #pragma unroll
            for (int u = 0; u < 8; ++u) {
                uint2 e = stage[grp][j + 2 * u + q];   // uniform per half
                unsigned eb = e.y;
                av[u] = *(const __half2*)&eb;
                mv[u] = Mh2[e.x * 16 + c];             // 8 half2 gathers in flight
            }
            #pragma unroll
            for (int u = 0; u < 8; ++u) {
                __half2 arg = __hadd2(__hfma2(av[u], we2, cnst2), mv[u]);
                __half2 ex  = h2exp2(arg);             // dummy: inf -> rr = 0
                acc2 = __hadd2(acc2, h2rcp(__hadd2(ex, one2)));
            }
        }
        fx += __low2float(acc2);                  // flush per 32-edge chunk
        fy += __high2float(acc2);
    }
    fx += __shfl_xor(fx, 16, 32);
    fy += __shfl_xor(fy, 16, 32);
    float deg = (float)(e1 - e0);
    if (l < 16)
        ((__half2*)simh)[n * 16 + c] =
            __floats2half2_rn(fmaf(-2.0f, fx, deg), fmaf(-2.0f, fy, deg));
}

// h_next[n] = sum over in-edges of sim[src]; 8 half2 gathers in flight;
// packed f32 accumulate; optionally fused next-layer GEMM (pre-scaled)
template <int FUSE>
__global__ void k_prop_gemm(const __half* __restrict__ simh, const int* __restrict__ off,
                            const int* __restrict__ srcs, const float* __restrict__ p,
                            const float* __restrict__ Wx, const float* __restrict__ Wp,
                            __half* __restrict__ outMh, float* __restrict__ outF,
                            int N) {
    __shared__ float sWx[1024];
    __shared__ int stageS[8][32];
    if (FUSE) {
        for (int i = threadIdx.x; i < 1024; i += blockDim.x) sWx[i] = Wx[i] * TANH_SCALE;
        __syncthreads();
    }
    const int l = threadIdx.x & 31;
    const int c = l & 15;
    const int q = l >> 4;
    const int grp = threadIdx.x >> 5;
    int n = blockIdx.x * 8 + grp;
    if (n >= N) return;

    const __half2* sim2 = (const __half2*)simh;
    f32x2 facc = {0.0f, 0.0f};
    int e0 = off[n], e1 = off[n + 1];
    for (int base = e0; base < e1; base += 32) {
        int m = min(32, e1 - base);
        stageS[grp][l] = (l < m) ? srcs[base + l] : N;   // dummy row -> +0
        for (int j = 0; j < m; j += 16) {
            __half2 v[8];
            #pragma unroll
            for (int u = 0; u < 8; ++u) {
                int s = stageS[grp][j + 2 * u + q];
                v[u] = sim2[s * 16 + c];               // 8 half2 gathers in flight
            }
            #pragma unroll
            for (int u = 0; u < 8; ++u) {
                float2 fv = __half22float2(v[u]);
                f32x2 t = {fv.x, fv.y};
                pk_add(facc, t);                       // exact packed f32 add
            }
        }
    }
    float fx = facc.x, fy = facc.y;
    fx += __shfl_xor(fx, 16, 32);
    fy += __shfl_xor(fy, 16, 32);

    if (!FUSE) {
        if (l < 16) ((float2*)outF)[n * 16 + c] = make_float2(fx, fy);
        return;
    }
    float mm = 0.0f;
    #pragma unroll
    for (int i = 0; i < 16; ++i) {
        float hx = __shfl(fx, i, 32);                  // h[2i]
        float hy = __shfl(fy, i, 32);                  // h[2i+1]
        mm = fmaf(hx, sWx[(2 * i) * 32 + l], mm);
        mm = fmaf(hy, sWx[(2 * i + 1) * 32 + l], mm);
    }
    float pv = (l < 3) ? p[n * 3 + l] : 0.0f;
    float pp = __shfl(pv, 0, 32) * Wp[l] + __shfl(pv, 1, 32) * Wp[32 + l]
             + __shfl(pv, 2, 32) * Wp[64 + l];
    mm = fmaf(pp, TANH_SCALE, mm);
    outMh[n * 32 + l] = __float2half(mm);
}

// ---------------- pooling + head ----------------

__global__ void k_pool(const float* __restrict__ h, const int* __restrict__ batch,
                       const float* __restrict__ Wh, const float* __restrict__ bh,
                       float* __restrict__ out, int n_nodes, int n_graphs) {
    __shared__ int sLo, sHi;
    __shared__ float red[256];
    int g = blockIdx.x;
    if (threadIdx.x == 0) {
        int lo = 0, hi = n_nodes;
        while (lo < hi) { int m = (lo + hi) >> 1; if (batch[m] < g) lo = m + 1; else hi = m; }
        sLo = lo;
        lo = 0; hi = n_nodes; int g1 = g + 1;
        while (lo < hi) { int m = (lo + hi) >> 1; if (batch[m] < g1) lo = m + 1; else hi = m; }
        sHi = lo;
    }
    __syncthreads();
    int lo = sLo, hi = sHi;
    int k = threadIdx.x & 31, r = threadIdx.x >> 5;
    float acc = 0.0f;
    for (int n = lo + r; n < hi; n += 8) acc += h[n * 32 + k];
    red[threadIdx.x] = acc;
    __syncthreads();
    if (threadIdx.x < 32) {
        float s = 0.0f;
        #pragma unroll
        for (int r2 = 0; r2 < 8; ++r2) s += red[r2 * 32 + k];
        float c = (float)(hi - lo);
        float rep = s / fmaxf(c, 1.0f);
        out[n_graphs + g * 32 + k] = rep;
        float t = rep * Wh[k];
        #pragma unroll
        for (int d = 16; d > 0; d >>= 1) t += __shfl_down(t, d, 32);
        if (k == 0) out[g] = t + bh[0];
    }
}

// ---------------- launch ----------------

extern "C" void kernel_launch(void* const* d_in, const int* in_sizes, int n_in,
                              void* d_out, int out_size, void* d_ws, size_t ws_size,
                              hipStream_t stream) {
    const float* x   = (const float*)d_in[0];
    const float* p   = (const float*)d_in[1];
    const float* ea  = (const float*)d_in[2];
    const float* Wx0 = (const float*)d_in[3];
    const float* Wx1 = (const float*)d_in[4];
    const float* Wx2 = (const float*)d_in[5];
    const float* Wp0 = (const float*)d_in[6];
    const float* Wp1 = (const float*)d_in[7];
    const float* Wp2 = (const float*)d_in[8];
    const float* We0 = (const float*)d_in[9];
    const float* We1 = (const float*)d_in[10];
    const float* We2 = (const float*)d_in[11];
    const float* b0  = (const float*)d_in[12];
    const float* b1  = (const float*)d_in[13];
    const float* b2  = (const float*)d_in[14];
    const float* Wh  = (const float*)d_in[15];
    const float* bh  = (const float*)d_in[16];
    const int* edge_index = (const int*)d_in[17];
    const int* batch      = (const int*)d_in[18];

    const int N = in_sizes[0] / 5;
    const int E = in_sizes[17] / 2;
    const int G = out_size / 33;
    const int nbuck = (N + BN - 1) / BN;     // 391 for N=100000

    const int* srcp = edge_index;
    const int* dstp = edge_index + E;

    char* w = (char*)d_ws;
    auto alloc = [&](size_t bytes) -> void* {
        void* r = (void*)w;
        w += (bytes + 255) & ~(size_t)255;
        return r;
    };
    int*    bcnt  = (int*)alloc((size_t)nbuck * 4);
    int*    boff  = (int*)alloc((size_t)(nbuck + 1) * 4);
    int*    gcur  = (int*)alloc((size_t)nbuck * 4);
    int*    off   = (int*)alloc((size_t)(N + 1) * 4);
    uint2*  rec   = (uint2*)alloc((size_t)E * 8);
    uint2*  rec2  = (uint2*)alloc((size_t)E * 8);
    int*    srcs2 = (int*)alloc((size_t)E * 4);
    __half* Mh    = (__half*)alloc((size_t)(N + 1) * K_DIM * 2);   // +dummy row
    __half* simh  = (__half*)alloc((size_t)(N + 1) * K_DIM * 2);   // +dummy row
    float*  hB    = (float*)alloc((size_t)N * K_DIM * 4);

    // build: bucket sort (BN=256) -> within-bucket node sort (LDS-staged) -> CSR
    (void)hipMemsetAsync(bcnt, 0, (size_t)nbuck * 4, stream);
    k_bcnt<<<1024, 256, 0, stream>>>(dstp, bcnt, E, nbuck);
    k_bscan<<<1, 256, 0, stream>>>(bcnt, boff, gcur, nbuck, E);
    k_bscatter<<<256, 1024, 0, stream>>>(srcp, dstp, ea, gcur, rec, E, nbuck);
    k_blocal<<<nbuck, 256, 0, stream>>>(rec, rec2, srcs2, boff, off, N, E);
    k_initdummy<<<1, 32, 0, stream>>>(Mh, simh, N);

    const int NB = (N + 7) / 8;   // 8 node-groups (32 lanes) per 256-thread block

    // layer 0
    k_node_gemm5<<<NB, 256, 0, stream>>>(x, p, Wx0, Wp0, Mh, N);
    k_edge_msg<<<NB, 256, 0, stream>>>(Mh, p, off, rec2, Wp0, We0, b0, simh, N);
    k_prop_gemm<1><<<NB, 256, 0, stream>>>(simh, off, srcs2, p, Wx1, Wp1, Mh, nullptr, N);
    // layer 1
    k_edge_msg<<<NB, 256, 0, stream>>>(Mh, p, off, rec2, Wp1, We1, b1, simh, N);
    k_prop_gemm<1><<<NB, 256, 0, stream>>>(simh, off, srcs2, p, Wx2, Wp2, Mh, nullptr, N);
    // layer 2
    k_edge_msg<<<NB, 256, 0, stream>>>(Mh, p, off, rec2, Wp2, We2, b2, simh, N);
    k_prop_gemm<0><<<NB, 256, 0, stream>>>(simh, off, srcs2, p, nullptr, nullptr, nullptr, hB, N);

    // pool + head
    k_pool<<<G, 256, 0, stream>>>(hB, batch, Wh, bh, (float*)d_out, N, G);
}